// Round 11
// baseline (394.586 us; speedup 1.0000x reference)
//
#include <hip/hip_runtime.h>
#include <hip/hip_bf16.h>
#include <hip/hip_fp16.h>
#include <math.h>

#define HID 64

#if defined(__has_builtin)
#if __has_builtin(__builtin_amdgcn_cvt_pk_f32_fp8) && __has_builtin(__builtin_amdgcn_cvt_pk_fp8_f32)
#define HWFP8 1
#endif
#endif

typedef float vfloat2 __attribute__((ext_vector_type(2)));

// ---------------- helpers ----------------

__device__ __forceinline__ unsigned short f2bf(float x) {
    unsigned int u = __float_as_uint(x);
    unsigned int r = u + 0x7fffu + ((u >> 16) & 1u);   // RNE
    return (unsigned short)(r >> 16);
}

#ifndef HWFP8
__device__ __forceinline__ unsigned int enc8_sw(float a) {
    unsigned short hb = __half_as_ushort(__float2half(a));
    unsigned int r = (unsigned int)hb + 0x7fu + ((hb >> 8) & 1u);
    return (r >> 8) & 0xffu;
}
__device__ __forceinline__ float dec8_sw(unsigned int b) {
    return __half2float(__ushort_as_half((unsigned short)(b << 8)));
}
#endif

__device__ __forceinline__ unsigned int enc4(float a, float b, float c, float d) {
#ifdef HWFP8
    int r = __builtin_amdgcn_cvt_pk_fp8_f32(a, b, 0, false);
    r = __builtin_amdgcn_cvt_pk_fp8_f32(c, d, r, true);
    return (unsigned int)r;
#else
    return enc8_sw(a) | (enc8_sw(b) << 8) | (enc8_sw(c) << 16) | (enc8_sw(d) << 24);
#endif
}

__device__ __forceinline__ void dec4(unsigned int w, float* f) {
#ifdef HWFP8
    vfloat2 a = __builtin_amdgcn_cvt_pk_f32_fp8((int)w, false);
    vfloat2 b = __builtin_amdgcn_cvt_pk_f32_fp8((int)w, true);
    f[0] = a.x; f[1] = a.y; f[2] = b.x; f[3] = b.y;
#else
    f[0] = dec8_sw(w & 0xffu); f[1] = dec8_sw((w >> 8) & 0xffu);
    f[2] = dec8_sw((w >> 16) & 0xffu); f[3] = dec8_sw(w >> 24);
#endif
}

__device__ __forceinline__ void dec8(uint2 g, float* f) {
    dec4(g.x, f);
    dec4(g.y, f + 4);
}

// ---------------- fused graph preprocessing ----------------

__global__ __launch_bounds__(256) void k_pre_count(const int* __restrict__ edst, int* __restrict__ deg, int E,
                                                   const int* __restrict__ pcol, int* __restrict__ ccnt, int P) {
    int gth = blockIdx.x * blockDim.x + threadIdx.x;
    int GT = gridDim.x * blockDim.x;
    for (int e = gth; e < E; e += GT) atomicAdd(&deg[edst[e]], 1);
    for (int p = gth; p < P; p += GT) atomicAdd(&ccnt[pcol[p]], 1);
}

__global__ __launch_bounds__(256) void k_pre_scan(const int* __restrict__ deg, int* __restrict__ rowoff, int N,
                                                  const int* __restrict__ ccnt, int* __restrict__ coff, int NC,
                                                  float* __restrict__ dinv) {
    __shared__ int part[256];
    int t = threadIdx.x;
    int gth = blockIdx.x * blockDim.x + t;
    int GT = gridDim.x * blockDim.x;
    for (int i = gth; i < N; i += GT) dinv[i] = rsqrtf((float)(deg[i] + 1));

    const int* cnt = nullptr; int* off = nullptr; int n = 0;
    if (blockIdx.x == 0)      { cnt = deg;  off = rowoff; n = N; }
    else if (blockIdx.x == 1) { cnt = ccnt; off = coff;   n = NC; }
    else return;

    int CH = (n + 255) >> 8;
    int lo = min(t * CH, n), hi = min(lo + CH, n);
    int sum = 0;
    for (int i = lo; i < hi; ++i) sum += cnt[i];
    part[t] = sum;
    __syncthreads();
    for (int o = 1; o < 256; o <<= 1) {
        int v = (t >= o) ? part[t - o] : 0;
        __syncthreads();
        part[t] += v;
        __syncthreads();
    }
    int run = (t == 0) ? 0 : part[t - 1];
    for (int i = lo; i < hi; ++i) { off[i] = run; run += cnt[i]; }
    if (t == 255) off[n] = run;
}

__global__ __launch_bounds__(256) void k_pre_scatter(const int* __restrict__ esrc, const int* __restrict__ edst,
                                                     const float* __restrict__ dinv, const int* __restrict__ rowoff,
                                                     int* __restrict__ fill, int* __restrict__ ssrc,
                                                     float* __restrict__ snorm, int E,
                                                     const int* __restrict__ prow, const int* __restrict__ pcol,
                                                     const int* __restrict__ coff, int* __restrict__ cfill,
                                                     int* __restrict__ crow, int P) {
    int gth = blockIdx.x * blockDim.x + threadIdx.x;
    int GT = gridDim.x * blockDim.x;
    for (int e = gth; e < E; e += GT) {
        int s = esrc[e], d = edst[e];
        int pos = rowoff[d] + atomicAdd(&fill[d], 1);
        ssrc[pos]  = s;
        snorm[pos] = dinv[s] * dinv[d];
    }
    for (int p = gth; p < P; p += GT) {
        int c = pcol[p];
        int pos = coff[c] + atomicAdd(&cfill[c], 1);
        crow[pos] = prow[p];
    }
}

// ---------------- GCN layer ----------------

// Register-tiled GEMM: Y[row, h] = (sum_k X[row, k] * W[k, h]) * S, Y stored fp8.
// MODE 0: X fp32 [b, n, k] (row = n*8+b). MODE 1: X bf16 [row, k].
template<int MODE>
__global__ __launch_bounds__(256) void k_gemm_rt(const void* __restrict__ Xv,
                                                 const float* __restrict__ W,
                                                 unsigned int* __restrict__ Yq,
                                                 float S, int N, int rowsTot) {
    __shared__ float sW[64 * 64];
    __shared__ float sXT[64 * 68];
    int t = threadIdx.x;
    int r0 = blockIdx.x * 64;

#pragma unroll
    for (int i = 0; i < 16; ++i) sW[t + i * 256] = W[t + i * 256];

    {
        int row = t & 63;
        int kg = t >> 6;
        int gr = r0 + row;
        bool ok = gr < rowsTot;
        const float* Xf = (const float*)Xv;
        const unsigned short* Xh = (const unsigned short*)Xv;
#pragma unroll
        for (int i = 0; i < 4; ++i) {
            int k = (kg + i * 4) * 4;
            float4 v = make_float4(0.f, 0.f, 0.f, 0.f);
            if (ok) {
                if (MODE == 0) {
                    int n = gr >> 3, b = gr & 7;
                    v = *(const float4*)&Xf[((size_t)b * N + n) * 64 + k];
                } else {
                    ushort4 u = *(const ushort4*)&Xh[(size_t)gr * 64 + k];
                    v.x = __uint_as_float(((unsigned int)u.x) << 16);
                    v.y = __uint_as_float(((unsigned int)u.y) << 16);
                    v.z = __uint_as_float(((unsigned int)u.z) << 16);
                    v.w = __uint_as_float(((unsigned int)u.w) << 16);
                }
            }
            sXT[(k + 0) * 68 + row] = v.x;
            sXT[(k + 1) * 68 + row] = v.y;
            sXT[(k + 2) * 68 + row] = v.z;
            sXT[(k + 3) * 68 + row] = v.w;
        }
    }
    __syncthreads();

    int ci = t & 15, ri = t >> 4;
    float acc[4][4] = {};
#pragma unroll 16
    for (int k = 0; k < 64; ++k) {
        float4 xr = *(const float4*)&sXT[k * 68 + ri * 4];
        float4 wc = *(const float4*)&sW[k * 64 + ci * 4];
        acc[0][0] = fmaf(xr.x, wc.x, acc[0][0]); acc[0][1] = fmaf(xr.x, wc.y, acc[0][1]);
        acc[0][2] = fmaf(xr.x, wc.z, acc[0][2]); acc[0][3] = fmaf(xr.x, wc.w, acc[0][3]);
        acc[1][0] = fmaf(xr.y, wc.x, acc[1][0]); acc[1][1] = fmaf(xr.y, wc.y, acc[1][1]);
        acc[1][2] = fmaf(xr.y, wc.z, acc[1][2]); acc[1][3] = fmaf(xr.y, wc.w, acc[1][3]);
        acc[2][0] = fmaf(xr.z, wc.x, acc[2][0]); acc[2][1] = fmaf(xr.z, wc.y, acc[2][1]);
        acc[2][2] = fmaf(xr.z, wc.z, acc[2][2]); acc[2][3] = fmaf(xr.z, wc.w, acc[2][3]);
        acc[3][0] = fmaf(xr.w, wc.x, acc[3][0]); acc[3][1] = fmaf(xr.w, wc.y, acc[3][1]);
        acc[3][2] = fmaf(xr.w, wc.z, acc[3][2]); acc[3][3] = fmaf(xr.w, wc.w, acc[3][3]);
    }

#pragma unroll
    for (int j = 0; j < 4; ++j) {
        int row = r0 + ri * 4 + j;
        if (row < rowsTot)
            Yq[(size_t)row * 16 + ci] =
                enc4(acc[j][0] * S, acc[j][1] * S, acc[j][2] * S, acc[j][3] * S);
    }
}

// 4 nodes per 256-thread block, one wave per node; fp8 messages.
// Double-buffered 8-batches: next batch's 8 gathers issued BEFORE decoding the
// current batch -> 16 loads in flight in steady state.
template<int LAYER, bool STORE>
__global__ __launch_bounds__(256) void k_agg(const uint2* __restrict__ Y,
                                             const int* __restrict__ rowoff,
                                             const int* __restrict__ ssrc,
                                             const float* __restrict__ snorm,
                                             const float* __restrict__ dinv,
                                             const float* __restrict__ bias,
                                             const float* __restrict__ fcW,
                                             uint4* __restrict__ O,
                                             float* __restrict__ sArr,
                                             float invS, int N) {
    int n = blockIdx.x * 4 + (threadIdx.x >> 6);
    if (n >= N) return;
    int lane = threadIdx.x & 63;
    int hb = (lane & 7) * 8;
    float bv[8], wv[8];
#pragma unroll
    for (int k = 0; k < 8; ++k) { bv[k] = bias[hb + k]; wv[k] = fcW[3 * (hb + k) + LAYER]; }

    float dn = dinv[n];
    float w0 = dn * dn;
    float acc[8], f[8];
    dec8(Y[(size_t)n * 64 + lane], f);
#pragma unroll
    for (int k = 0; k < 8; ++k) acc[k] = w0 * f[k];

    int beg = rowoff[n], end = rowoff[n + 1];
    int i = beg;
    float wA[8];
    uint2 gA[8];
    bool haveA = (i + 8 <= end);
    if (haveA) {
        int sA[8];
#pragma unroll
        for (int u = 0; u < 8; ++u) { sA[u] = ssrc[i + u]; wA[u] = snorm[i + u]; }
#pragma unroll
        for (int u = 0; u < 8; ++u) gA[u] = Y[(size_t)sA[u] * 64 + lane];
        i += 8;
    }
    while (haveA) {
        bool haveB = (i + 8 <= end);
        float wB[8];
        uint2 gB[8];
        if (haveB) {
            int sB[8];
#pragma unroll
            for (int u = 0; u < 8; ++u) { sB[u] = ssrc[i + u]; wB[u] = snorm[i + u]; }
#pragma unroll
            for (int u = 0; u < 8; ++u) gB[u] = Y[(size_t)sB[u] * 64 + lane];
            i += 8;
        }
#pragma unroll
        for (int u = 0; u < 8; ++u) {
            dec8(gA[u], f);
#pragma unroll
            for (int k = 0; k < 8; ++k) acc[k] = fmaf(wA[u], f[k], acc[k]);
        }
        if (haveB) {
#pragma unroll
            for (int u = 0; u < 8; ++u) { gA[u] = gB[u]; wA[u] = wB[u]; }
        }
        haveA = haveB;
    }
    for (; i < end; ++i) {
        int s = ssrc[i];
        float w = snorm[i];
        dec8(Y[(size_t)s * 64 + lane], f);
#pragma unroll
        for (int k = 0; k < 8; ++k) acc[k] = fmaf(w, f[k], acc[k]);
    }

    float sv = 0.f;
#pragma unroll
    for (int k = 0; k < 8; ++k) {
        float o = fmaxf(fmaf(acc[k], invS, bv[k]), 0.f);
        acc[k] = o;
        sv = fmaf(o, wv[k], sv);
    }
    if (STORE) {
        uint4 o;
        o.x = (unsigned int)f2bf(acc[0]) | ((unsigned int)f2bf(acc[1]) << 16);
        o.y = (unsigned int)f2bf(acc[2]) | ((unsigned int)f2bf(acc[3]) << 16);
        o.z = (unsigned int)f2bf(acc[4]) | ((unsigned int)f2bf(acc[5]) << 16);
        o.w = (unsigned int)f2bf(acc[6]) | ((unsigned int)f2bf(acc[7]) << 16);
        O[(size_t)n * 64 + lane] = o;
    }
    sv += __shfl_down(sv, 4, 64);
    sv += __shfl_down(sv, 2, 64);
    sv += __shfl_down(sv, 1, 64);
    if ((lane & 7) == 0) {
        int b = lane >> 3;
        float* sp = sArr + (size_t)n * 8 + b;
        if (LAYER == 0) *sp = sv;
        else            *sp += sv;
    }
}

// ---------------- pooling head ----------------

__global__ __launch_bounds__(64) void k_poolg(const float* __restrict__ sArr,
                                              const int* __restrict__ coff,
                                              const int* __restrict__ crow,
                                              float* __restrict__ hpoolT) {
    int c = blockIdx.x;
    int lane = threadIdx.x;
    int beg = coff[c], end = coff[c + 1];
    int b = lane & 7;
    float acc = 0.f;
    int i = beg + (lane >> 3);
    for (; i + 24 < end; i += 32) {
        int r0 = crow[i], r1 = crow[i + 8], r2 = crow[i + 16], r3 = crow[i + 24];
        float a0 = sArr[(size_t)r0 * 8 + b];
        float a1 = sArr[(size_t)r1 * 8 + b];
        float a2 = sArr[(size_t)r2 * 8 + b];
        float a3 = sArr[(size_t)r3 * 8 + b];
        acc += (a0 + a1) + (a2 + a3);
    }
    for (; i < end; i += 8) acc += sArr[(size_t)crow[i] * 8 + b];
    acc += __shfl_down(acc, 32, 64);
    acc += __shfl_down(acc, 16, 64);
    acc += __shfl_down(acc, 8, 64);
    if (lane < 8) {
        float inv = 1.f / fmaxf((float)(end - beg), 1.f);
        hpoolT[(size_t)c * 8 + b] = acc * inv;
    }
}

// partial l1 (parallel, 200 blocks) + last-done block runs l2+log_softmax.
__global__ __launch_bounds__(128) void k_l1f(const float* __restrict__ hpoolT,
                                             const float* __restrict__ fcb,
                                             const float* __restrict__ l1W,
                                             float* __restrict__ hpre,
                                             int* __restrict__ done,
                                             const float* __restrict__ l1b,
                                             const float* __restrict__ l2W,
                                             const float* __restrict__ l2b,
                                             float* __restrict__ out,
                                             int NC, int HFC, int bs, int NCLS,
                                             int CHUNK, int nBlocks) {
    __shared__ float hl[64];
    int b = blockIdx.y;
    int c0 = blockIdx.x * CHUNK;
    int j = threadIdx.x;
    int cend = min(c0 + CHUNK, NC);
    for (int c = c0 + j; c < cend; c += blockDim.x)
        hl[c - c0] = hpoolT[(size_t)c * 8 + b] + fcb[0];
    __syncthreads();
    float acc = 0.f;
    for (int c = c0; c < cend; ++c) acc = fmaf(hl[c - c0], l1W[(size_t)c * HFC + j], acc);
    atomicAdd(&hpre[(size_t)b * HFC + j], acc);

    // ---- last-done election ----
    __threadfence();
    __syncthreads();
    __shared__ int amLast;
    if (j == 0) amLast = (atomicAdd(done, 1) == nBlocks - 1);
    __syncthreads();
    if (!amLast) return;
    __threadfence();

    // ---- final: relu(l1) -> l2 -> log_softmax (128 threads, 2k MACs) ----
    __shared__ float sZ[64];
    int g = j >> 3, l8 = j & 7;        // 16 groups x 8 lanes
    int nout = bs * NCLS;
    float v = 0.f;
    int b2 = g / NCLS, k2 = g - b2 * NCLS;
    if (g < nout) {
        for (int jj = l8; jj < HFC; jj += 8) {
            float h = fmaxf(hpre[(size_t)b2 * HFC + jj] + l1b[jj], 0.f);
            v = fmaf(h, l2W[(size_t)jj * NCLS + k2], v);
        }
    }
    v += __shfl_down(v, 4, 8);
    v += __shfl_down(v, 2, 8);
    v += __shfl_down(v, 1, 8);
    if (l8 == 0 && g < nout) sZ[g] = v + l2b[k2];
    __syncthreads();
    if (j < bs) {
        float m = -1e30f;
        for (int c = 0; c < NCLS; ++c) m = fmaxf(m, sZ[j * NCLS + c]);
        float s = 0.f;
        for (int c = 0; c < NCLS; ++c) s += expf(sZ[j * NCLS + c] - m);
        float lse = m + logf(s);
        for (int c = 0; c < NCLS; ++c) out[j * NCLS + c] = sZ[j * NCLS + c] - lse;
    }
}

// ---------------- launcher ----------------

extern "C" void kernel_launch(void* const* d_in, const int* in_sizes, int n_in,
                              void* d_out, int out_size, void* d_ws, size_t ws_size,
                              hipStream_t stream) {
    const float* x   = (const float*)d_in[0];
    const int* eidx  = (const int*)d_in[2];
    const int* prow  = (const int*)d_in[3];
    const int* pcol  = (const int*)d_in[4];
    const float* W1  = (const float*)d_in[5];
    const float* b1  = (const float*)d_in[6];
    const float* W2  = (const float*)d_in[7];
    const float* b2  = (const float*)d_in[8];
    const float* W3  = (const float*)d_in[9];
    const float* b3  = (const float*)d_in[10];
    const float* fcW = (const float*)d_in[11];
    const float* fcb = (const float*)d_in[12];
    const float* l1W = (const float*)d_in[13];
    const float* l1b = (const float*)d_in[14];
    const float* l2W = (const float*)d_in[15];
    const float* l2b = (const float*)d_in[16];
    float* out = (float*)d_out;

    const int bs   = in_sizes[1];                 // 8
    const int E    = in_sizes[2] / 2;
    const int P    = in_sizes[3];
    const int N    = in_sizes[0] / (bs * HID);
    const int HFC  = in_sizes[14];                // 128
    const int NC   = in_sizes[13] / HFC;          // 1000
    const int NCLS = in_sizes[15] / HFC;          // 2
    const int rows = N * bs;

    const int* esrc = eidx;
    const int* edst = eidx + E;

    size_t off = 0;
    auto alloc = [&](size_t bytes) -> void* {
        void* r = (char*)d_ws + off;
        off += (bytes + 255) & ~(size_t)255;
        return r;
    };
    // ---- zero region (one memset) ----
    char* zbase   = (char*)d_ws;
    int*   deg    = (int*)  alloc((size_t)N * 4);
    int*   fill   = (int*)  alloc((size_t)N * 4);
    int*   ccnt   = (int*)  alloc((size_t)NC * 4);
    int*   cfill  = (int*)  alloc((size_t)NC * 4);
    float* hpre   = (float*)alloc((size_t)bs * HFC * 4);
    int*   done   = (int*)  alloc(4);
    size_t zspan  = off;
    // ---- rest ----
    float* dinv   = (float*)alloc((size_t)N * 4);
    int*   rowoff = (int*)  alloc(((size_t)N + 1) * 4);
    int*   coff   = (int*)  alloc(((size_t)NC + 1) * 4);
    int*   crow   = (int*)  alloc((size_t)P * 4);
    float* hpoolT = (float*)alloc((size_t)NC * bs * 4);
    int*   ssrc   = (int*)  alloc((size_t)E * 4);
    float* snorm  = (float*)alloc((size_t)E * 4);
    unsigned int* Yq   = (unsigned int*)alloc((size_t)rows * HID);
    unsigned short* X1 = (unsigned short*)alloc((size_t)rows * HID * 2);
    unsigned short* X2 = (unsigned short*)alloc((size_t)rows * HID * 2);
    float* sArr   = (float*)alloc((size_t)rows * 4);

    hipMemsetAsync(zbase, 0, zspan, stream);

    int gPre = 512;
    k_pre_count<<<gPre, 256, 0, stream>>>(edst, deg, E, pcol, ccnt, P);
    k_pre_scan<<<64, 256, 0, stream>>>(deg, rowoff, N, ccnt, coff, NC, dinv);
    k_pre_scatter<<<gPre, 256, 0, stream>>>(esrc, edst, dinv, rowoff, fill, ssrc, snorm, E,
                                            prow, pcol, coff, cfill, crow, P);

    const float S1 = 1.f,  iS1 = 1.f;
    const float S2 = 16.f, iS2 = 1.f / 16.f;
    const float S3 = 128.f, iS3 = 1.f / 128.f;

    int gG = (rows + 63) / 64;
    int gA = (N + 3) / 4;
    k_gemm_rt<0><<<gG, 256, 0, stream>>>(x, W1, Yq, S1, N, rows);
    k_agg<0, true><<<gA, 256, 0, stream>>>((const uint2*)Yq, rowoff, ssrc, snorm, dinv, b1, fcW, (uint4*)X1, sArr, iS1, N);
    k_gemm_rt<1><<<gG, 256, 0, stream>>>(X1, W2, Yq, S2, N, rows);
    k_agg<1, true><<<gA, 256, 0, stream>>>((const uint2*)Yq, rowoff, ssrc, snorm, dinv, b2, fcW, (uint4*)X2, sArr, iS2, N);
    k_gemm_rt<1><<<gG, 256, 0, stream>>>(X2, W3, Yq, S3, N, rows);
    k_agg<2, false><<<gA, 256, 0, stream>>>((const uint2*)Yq, rowoff, ssrc, snorm, dinv, b3, fcW, nullptr, sArr, iS3, N);

    k_poolg<<<NC, 64, 0, stream>>>(sArr, coff, crow, hpoolT);

    const int CHUNK = 40;
    dim3 gL1((NC + CHUNK - 1) / CHUNK, bs);
    int nBlocks = gL1.x * gL1.y;   // 200
    k_l1f<<<gL1, 128, 0, stream>>>(hpoolT, fcb, l1W, hpre, done, l1b, l2W, l2b, out,
                                   NC, HFC, bs, NCLS, CHUNK, nBlocks);
}

// Round 12
// 374.043 us; speedup vs baseline: 1.0549x; 1.0549x over previous
//
#include <hip/hip_runtime.h>
#include <hip/hip_bf16.h>
#include <hip/hip_fp16.h>
#include <math.h>

#define HID 64

#if defined(__has_builtin)
#if __has_builtin(__builtin_amdgcn_cvt_pk_f32_fp8) && __has_builtin(__builtin_amdgcn_cvt_pk_fp8_f32)
#define HWFP8 1
#endif
#endif

typedef float vfloat2 __attribute__((ext_vector_type(2)));

// ---------------- helpers ----------------

__device__ __forceinline__ unsigned short f2bf(float x) {
    unsigned int u = __float_as_uint(x);
    unsigned int r = u + 0x7fffu + ((u >> 16) & 1u);   // RNE
    return (unsigned short)(r >> 16);
}

#ifndef HWFP8
__device__ __forceinline__ unsigned int enc8_sw(float a) {
    unsigned short hb = __half_as_ushort(__float2half(a));
    unsigned int r = (unsigned int)hb + 0x7fu + ((hb >> 8) & 1u);
    return (r >> 8) & 0xffu;
}
__device__ __forceinline__ float dec8_sw(unsigned int b) {
    return __half2float(__ushort_as_half((unsigned short)(b << 8)));
}
#endif

__device__ __forceinline__ unsigned int enc4(float a, float b, float c, float d) {
#ifdef HWFP8
    int r = __builtin_amdgcn_cvt_pk_fp8_f32(a, b, 0, false);
    r = __builtin_amdgcn_cvt_pk_fp8_f32(c, d, r, true);
    return (unsigned int)r;
#else
    return enc8_sw(a) | (enc8_sw(b) << 8) | (enc8_sw(c) << 16) | (enc8_sw(d) << 24);
#endif
}

__device__ __forceinline__ void dec4(unsigned int w, float* f) {
#ifdef HWFP8
    vfloat2 a = __builtin_amdgcn_cvt_pk_f32_fp8((int)w, false);
    vfloat2 b = __builtin_amdgcn_cvt_pk_f32_fp8((int)w, true);
    f[0] = a.x; f[1] = a.y; f[2] = b.x; f[3] = b.y;
#else
    f[0] = dec8_sw(w & 0xffu); f[1] = dec8_sw((w >> 8) & 0xffu);
    f[2] = dec8_sw((w >> 16) & 0xffu); f[3] = dec8_sw(w >> 24);
#endif
}

__device__ __forceinline__ void dec8(uint2 g, float* f) {
    dec4(g.x, f);
    dec4(g.y, f + 4);
}

// ---------------- fused graph preprocessing ----------------

__global__ __launch_bounds__(256) void k_pre_count(const int* __restrict__ edst, int* __restrict__ deg, int E,
                                                   const int* __restrict__ pcol, int* __restrict__ ccnt, int P) {
    int gth = blockIdx.x * blockDim.x + threadIdx.x;
    int GT = gridDim.x * blockDim.x;
    for (int e = gth; e < E; e += GT) atomicAdd(&deg[edst[e]], 1);
    for (int p = gth; p < P; p += GT) atomicAdd(&ccnt[pcol[p]], 1);
}

__global__ __launch_bounds__(256) void k_pre_scan(const int* __restrict__ deg, int* __restrict__ rowoff, int N,
                                                  const int* __restrict__ ccnt, int* __restrict__ coff, int NC,
                                                  float* __restrict__ dinv) {
    __shared__ int part[256];
    int t = threadIdx.x;
    int gth = blockIdx.x * blockDim.x + t;
    int GT = gridDim.x * blockDim.x;
    for (int i = gth; i < N; i += GT) dinv[i] = rsqrtf((float)(deg[i] + 1));

    const int* cnt = nullptr; int* off = nullptr; int n = 0;
    if (blockIdx.x == 0)      { cnt = deg;  off = rowoff; n = N; }
    else if (blockIdx.x == 1) { cnt = ccnt; off = coff;   n = NC; }
    else return;

    int CH = (n + 255) >> 8;
    int lo = min(t * CH, n), hi = min(lo + CH, n);
    int sum = 0;
    for (int i = lo; i < hi; ++i) sum += cnt[i];
    part[t] = sum;
    __syncthreads();
    for (int o = 1; o < 256; o <<= 1) {
        int v = (t >= o) ? part[t - o] : 0;
        __syncthreads();
        part[t] += v;
        __syncthreads();
    }
    int run = (t == 0) ? 0 : part[t - 1];
    for (int i = lo; i < hi; ++i) { off[i] = run; run += cnt[i]; }
    if (t == 255) off[n] = run;
}

__global__ __launch_bounds__(256) void k_pre_scatter(const int* __restrict__ esrc, const int* __restrict__ edst,
                                                     const float* __restrict__ dinv, const int* __restrict__ rowoff,
                                                     int* __restrict__ fill, int* __restrict__ ssrc,
                                                     float* __restrict__ snorm, int E,
                                                     const int* __restrict__ prow, const int* __restrict__ pcol,
                                                     const int* __restrict__ coff, int* __restrict__ cfill,
                                                     int* __restrict__ crow, int P) {
    int gth = blockIdx.x * blockDim.x + threadIdx.x;
    int GT = gridDim.x * blockDim.x;
    for (int e = gth; e < E; e += GT) {
        int s = esrc[e], d = edst[e];
        int pos = rowoff[d] + atomicAdd(&fill[d], 1);
        ssrc[pos]  = s;
        snorm[pos] = dinv[s] * dinv[d];
    }
    for (int p = gth; p < P; p += GT) {
        int c = pcol[p];
        int pos = coff[c] + atomicAdd(&cfill[c], 1);
        crow[pos] = prow[p];
    }
}

// ---------------- GCN layer ----------------

// Register-tiled GEMM: Y[row, h] = (sum_k X[row, k] * W[k, h]) * S, Y stored fp8.
// MODE 0: X fp32 [b, n, k] (row = n*8+b). MODE 1: X bf16 [row, k].
template<int MODE>
__global__ __launch_bounds__(256) void k_gemm_rt(const void* __restrict__ Xv,
                                                 const float* __restrict__ W,
                                                 unsigned int* __restrict__ Yq,
                                                 float S, int N, int rowsTot) {
    __shared__ float sW[64 * 64];
    __shared__ float sXT[64 * 68];
    int t = threadIdx.x;
    int r0 = blockIdx.x * 64;

#pragma unroll
    for (int i = 0; i < 16; ++i) sW[t + i * 256] = W[t + i * 256];

    {
        int row = t & 63;
        int kg = t >> 6;
        int gr = r0 + row;
        bool ok = gr < rowsTot;
        const float* Xf = (const float*)Xv;
        const unsigned short* Xh = (const unsigned short*)Xv;
#pragma unroll
        for (int i = 0; i < 4; ++i) {
            int k = (kg + i * 4) * 4;
            float4 v = make_float4(0.f, 0.f, 0.f, 0.f);
            if (ok) {
                if (MODE == 0) {
                    int n = gr >> 3, b = gr & 7;
                    v = *(const float4*)&Xf[((size_t)b * N + n) * 64 + k];
                } else {
                    ushort4 u = *(const ushort4*)&Xh[(size_t)gr * 64 + k];
                    v.x = __uint_as_float(((unsigned int)u.x) << 16);
                    v.y = __uint_as_float(((unsigned int)u.y) << 16);
                    v.z = __uint_as_float(((unsigned int)u.z) << 16);
                    v.w = __uint_as_float(((unsigned int)u.w) << 16);
                }
            }
            sXT[(k + 0) * 68 + row] = v.x;
            sXT[(k + 1) * 68 + row] = v.y;
            sXT[(k + 2) * 68 + row] = v.z;
            sXT[(k + 3) * 68 + row] = v.w;
        }
    }
    __syncthreads();

    int ci = t & 15, ri = t >> 4;
    float acc[4][4] = {};
#pragma unroll 16
    for (int k = 0; k < 64; ++k) {
        float4 xr = *(const float4*)&sXT[k * 68 + ri * 4];
        float4 wc = *(const float4*)&sW[k * 64 + ci * 4];
        acc[0][0] = fmaf(xr.x, wc.x, acc[0][0]); acc[0][1] = fmaf(xr.x, wc.y, acc[0][1]);
        acc[0][2] = fmaf(xr.x, wc.z, acc[0][2]); acc[0][3] = fmaf(xr.x, wc.w, acc[0][3]);
        acc[1][0] = fmaf(xr.y, wc.x, acc[1][0]); acc[1][1] = fmaf(xr.y, wc.y, acc[1][1]);
        acc[1][2] = fmaf(xr.y, wc.z, acc[1][2]); acc[1][3] = fmaf(xr.y, wc.w, acc[1][3]);
        acc[2][0] = fmaf(xr.z, wc.x, acc[2][0]); acc[2][1] = fmaf(xr.z, wc.y, acc[2][1]);
        acc[2][2] = fmaf(xr.z, wc.z, acc[2][2]); acc[2][3] = fmaf(xr.z, wc.w, acc[2][3]);
        acc[3][0] = fmaf(xr.w, wc.x, acc[3][0]); acc[3][1] = fmaf(xr.w, wc.y, acc[3][1]);
        acc[3][2] = fmaf(xr.w, wc.z, acc[3][2]); acc[3][3] = fmaf(xr.w, wc.w, acc[3][3]);
    }

#pragma unroll
    for (int j = 0; j < 4; ++j) {
        int row = r0 + ri * 4 + j;
        if (row < rowsTot)
            Yq[(size_t)row * 16 + ci] =
                enc4(acc[j][0] * S, acc[j][1] * S, acc[j][2] * S, acc[j][3] * S);
    }
}

// 4 nodes per 256-thread block, one wave per node; fp8 messages; 8-deep edge pipeline.
// (round-7 version — best measured; 16-deep double-buffer regressed in R11: +40 VGPR
// cost more than the extra overlap bought — grid-level MLP already saturates L2/L3)
template<int LAYER, bool STORE>
__global__ __launch_bounds__(256) void k_agg(const uint2* __restrict__ Y,
                                             const int* __restrict__ rowoff,
                                             const int* __restrict__ ssrc,
                                             const float* __restrict__ snorm,
                                             const float* __restrict__ dinv,
                                             const float* __restrict__ bias,
                                             const float* __restrict__ fcW,
                                             uint4* __restrict__ O,
                                             float* __restrict__ sArr,
                                             float invS, int N) {
    int n = blockIdx.x * 4 + (threadIdx.x >> 6);
    if (n >= N) return;
    int lane = threadIdx.x & 63;
    int hb = (lane & 7) * 8;
    float bv[8], wv[8];
#pragma unroll
    for (int k = 0; k < 8; ++k) { bv[k] = bias[hb + k]; wv[k] = fcW[3 * (hb + k) + LAYER]; }

    float dn = dinv[n];
    float w0 = dn * dn;
    float acc[8], f[8];
    dec8(Y[(size_t)n * 64 + lane], f);
#pragma unroll
    for (int k = 0; k < 8; ++k) acc[k] = w0 * f[k];

    int beg = rowoff[n], end = rowoff[n + 1];
    int i = beg;
    for (; i + 7 < end; i += 8) {
        int   sI[8];
        float wI[8];
        uint2 g[8];
#pragma unroll
        for (int u = 0; u < 8; ++u) { sI[u] = ssrc[i + u]; wI[u] = snorm[i + u]; }
#pragma unroll
        for (int u = 0; u < 8; ++u) g[u] = Y[(size_t)sI[u] * 64 + lane];
#pragma unroll
        for (int u = 0; u < 8; ++u) {
            dec8(g[u], f);
#pragma unroll
            for (int k = 0; k < 8; ++k) acc[k] = fmaf(wI[u], f[k], acc[k]);
        }
    }
    for (; i < end; ++i) {
        int s = ssrc[i];
        float w = snorm[i];
        dec8(Y[(size_t)s * 64 + lane], f);
#pragma unroll
        for (int k = 0; k < 8; ++k) acc[k] = fmaf(w, f[k], acc[k]);
    }

    float sv = 0.f;
#pragma unroll
    for (int k = 0; k < 8; ++k) {
        float o = fmaxf(fmaf(acc[k], invS, bv[k]), 0.f);
        acc[k] = o;
        sv = fmaf(o, wv[k], sv);
    }
    if (STORE) {
        uint4 o;
        o.x = (unsigned int)f2bf(acc[0]) | ((unsigned int)f2bf(acc[1]) << 16);
        o.y = (unsigned int)f2bf(acc[2]) | ((unsigned int)f2bf(acc[3]) << 16);
        o.z = (unsigned int)f2bf(acc[4]) | ((unsigned int)f2bf(acc[5]) << 16);
        o.w = (unsigned int)f2bf(acc[6]) | ((unsigned int)f2bf(acc[7]) << 16);
        O[(size_t)n * 64 + lane] = o;
    }
    sv += __shfl_down(sv, 4, 64);
    sv += __shfl_down(sv, 2, 64);
    sv += __shfl_down(sv, 1, 64);
    if ((lane & 7) == 0) {
        int b = lane >> 3;
        float* sp = sArr + (size_t)n * 8 + b;
        if (LAYER == 0) *sp = sv;
        else            *sp += sv;
    }
}

// ---------------- pooling head ----------------

__global__ __launch_bounds__(64) void k_poolg(const float* __restrict__ sArr,
                                              const int* __restrict__ coff,
                                              const int* __restrict__ crow,
                                              float* __restrict__ hpoolT) {
    int c = blockIdx.x;
    int lane = threadIdx.x;
    int beg = coff[c], end = coff[c + 1];
    int b = lane & 7;
    float acc = 0.f;
    int i = beg + (lane >> 3);
    for (; i + 24 < end; i += 32) {
        int r0 = crow[i], r1 = crow[i + 8], r2 = crow[i + 16], r3 = crow[i + 24];
        float a0 = sArr[(size_t)r0 * 8 + b];
        float a1 = sArr[(size_t)r1 * 8 + b];
        float a2 = sArr[(size_t)r2 * 8 + b];
        float a3 = sArr[(size_t)r3 * 8 + b];
        acc += (a0 + a1) + (a2 + a3);
    }
    for (; i < end; i += 8) acc += sArr[(size_t)crow[i] * 8 + b];
    acc += __shfl_down(acc, 32, 64);
    acc += __shfl_down(acc, 16, 64);
    acc += __shfl_down(acc, 8, 64);
    if (lane < 8) {
        float inv = 1.f / fmaxf((float)(end - beg), 1.f);
        hpoolT[(size_t)c * 8 + b] = acc * inv;
    }
}

// partial l1 (parallel, 200 blocks) + last-done block runs l2+log_softmax.
__global__ __launch_bounds__(128) void k_l1f(const float* __restrict__ hpoolT,
                                             const float* __restrict__ fcb,
                                             const float* __restrict__ l1W,
                                             float* __restrict__ hpre,
                                             int* __restrict__ done,
                                             const float* __restrict__ l1b,
                                             const float* __restrict__ l2W,
                                             const float* __restrict__ l2b,
                                             float* __restrict__ out,
                                             int NC, int HFC, int bs, int NCLS,
                                             int CHUNK, int nBlocks) {
    __shared__ float hl[64];
    int b = blockIdx.y;
    int c0 = blockIdx.x * CHUNK;
    int j = threadIdx.x;
    int cend = min(c0 + CHUNK, NC);
    for (int c = c0 + j; c < cend; c += blockDim.x)
        hl[c - c0] = hpoolT[(size_t)c * 8 + b] + fcb[0];
    __syncthreads();
    float acc = 0.f;
    for (int c = c0; c < cend; ++c) acc = fmaf(hl[c - c0], l1W[(size_t)c * HFC + j], acc);
    atomicAdd(&hpre[(size_t)b * HFC + j], acc);

    // ---- last-done election ----
    __threadfence();
    __syncthreads();
    __shared__ int amLast;
    if (j == 0) amLast = (atomicAdd(done, 1) == nBlocks - 1);
    __syncthreads();
    if (!amLast) return;
    __threadfence();

    // ---- final: relu(l1) -> l2 -> log_softmax (128 threads, 2k MACs) ----
    __shared__ float sZ[64];
    int g = j >> 3, l8 = j & 7;        // 16 groups x 8 lanes
    int nout = bs * NCLS;
    float v = 0.f;
    int b2 = g / NCLS, k2 = g - b2 * NCLS;
    if (g < nout) {
        for (int jj = l8; jj < HFC; jj += 8) {
            float h = fmaxf(hpre[(size_t)b2 * HFC + jj] + l1b[jj], 0.f);
            v = fmaf(h, l2W[(size_t)jj * NCLS + k2], v);
        }
    }
    v += __shfl_down(v, 4, 8);
    v += __shfl_down(v, 2, 8);
    v += __shfl_down(v, 1, 8);
    if (l8 == 0 && g < nout) sZ[g] = v + l2b[k2];
    __syncthreads();
    if (j < bs) {
        float m = -1e30f;
        for (int c = 0; c < NCLS; ++c) m = fmaxf(m, sZ[j * NCLS + c]);
        float s = 0.f;
        for (int c = 0; c < NCLS; ++c) s += expf(sZ[j * NCLS + c] - m);
        float lse = m + logf(s);
        for (int c = 0; c < NCLS; ++c) out[j * NCLS + c] = sZ[j * NCLS + c] - lse;
    }
}

// ---------------- launcher ----------------

extern "C" void kernel_launch(void* const* d_in, const int* in_sizes, int n_in,
                              void* d_out, int out_size, void* d_ws, size_t ws_size,
                              hipStream_t stream) {
    const float* x   = (const float*)d_in[0];
    const int* eidx  = (const int*)d_in[2];
    const int* prow  = (const int*)d_in[3];
    const int* pcol  = (const int*)d_in[4];
    const float* W1  = (const float*)d_in[5];
    const float* b1  = (const float*)d_in[6];
    const float* W2  = (const float*)d_in[7];
    const float* b2  = (const float*)d_in[8];
    const float* W3  = (const float*)d_in[9];
    const float* b3  = (const float*)d_in[10];
    const float* fcW = (const float*)d_in[11];
    const float* fcb = (const float*)d_in[12];
    const float* l1W = (const float*)d_in[13];
    const float* l1b = (const float*)d_in[14];
    const float* l2W = (const float*)d_in[15];
    const float* l2b = (const float*)d_in[16];
    float* out = (float*)d_out;

    const int bs   = in_sizes[1];                 // 8
    const int E    = in_sizes[2] / 2;
    const int P    = in_sizes[3];
    const int N    = in_sizes[0] / (bs * HID);
    const int HFC  = in_sizes[14];                // 128
    const int NC   = in_sizes[13] / HFC;          // 1000
    const int NCLS = in_sizes[15] / HFC;          // 2
    const int rows = N * bs;

    const int* esrc = eidx;
    const int* edst = eidx + E;

    size_t off = 0;
    auto alloc = [&](size_t bytes) -> void* {
        void* r = (char*)d_ws + off;
        off += (bytes + 255) & ~(size_t)255;
        return r;
    };
    // ---- zero region (one memset) ----
    char* zbase   = (char*)d_ws;
    int*   deg    = (int*)  alloc((size_t)N * 4);
    int*   fill   = (int*)  alloc((size_t)N * 4);
    int*   ccnt   = (int*)  alloc((size_t)NC * 4);
    int*   cfill  = (int*)  alloc((size_t)NC * 4);
    float* hpre   = (float*)alloc((size_t)bs * HFC * 4);
    int*   done   = (int*)  alloc(4);
    size_t zspan  = off;
    // ---- rest ----
    float* dinv   = (float*)alloc((size_t)N * 4);
    int*   rowoff = (int*)  alloc(((size_t)N + 1) * 4);
    int*   coff   = (int*)  alloc(((size_t)NC + 1) * 4);
    int*   crow   = (int*)  alloc((size_t)P * 4);
    float* hpoolT = (float*)alloc((size_t)NC * bs * 4);
    int*   ssrc   = (int*)  alloc((size_t)E * 4);
    float* snorm  = (float*)alloc((size_t)E * 4);
    unsigned int* Yq   = (unsigned int*)alloc((size_t)rows * HID);
    unsigned short* X1 = (unsigned short*)alloc((size_t)rows * HID * 2);
    unsigned short* X2 = (unsigned short*)alloc((size_t)rows * HID * 2);
    float* sArr   = (float*)alloc((size_t)rows * 4);

    hipMemsetAsync(zbase, 0, zspan, stream);

    int gPre = 512;
    k_pre_count<<<gPre, 256, 0, stream>>>(edst, deg, E, pcol, ccnt, P);
    k_pre_scan<<<64, 256, 0, stream>>>(deg, rowoff, N, ccnt, coff, NC, dinv);
    k_pre_scatter<<<gPre, 256, 0, stream>>>(esrc, edst, dinv, rowoff, fill, ssrc, snorm, E,
                                            prow, pcol, coff, cfill, crow, P);

    const float S1 = 1.f,  iS1 = 1.f;
    const float S2 = 16.f, iS2 = 1.f / 16.f;
    const float S3 = 128.f, iS3 = 1.f / 128.f;

    int gG = (rows + 63) / 64;
    int gA = (N + 3) / 4;
    k_gemm_rt<0><<<gG, 256, 0, stream>>>(x, W1, Yq, S1, N, rows);
    k_agg<0, true><<<gA, 256, 0, stream>>>((const uint2*)Yq, rowoff, ssrc, snorm, dinv, b1, fcW, (uint4*)X1, sArr, iS1, N);
    k_gemm_rt<1><<<gG, 256, 0, stream>>>(X1, W2, Yq, S2, N, rows);
    k_agg<1, true><<<gA, 256, 0, stream>>>((const uint2*)Yq, rowoff, ssrc, snorm, dinv, b2, fcW, (uint4*)X2, sArr, iS2, N);
    k_gemm_rt<1><<<gG, 256, 0, stream>>>(X2, W3, Yq, S3, N, rows);
    k_agg<2, false><<<gA, 256, 0, stream>>>((const uint2*)Yq, rowoff, ssrc, snorm, dinv, b3, fcW, nullptr, sArr, iS3, N);

    k_poolg<<<NC, 64, 0, stream>>>(sArr, coff, crow, hpoolT);

    const int CHUNK = 40;
    dim3 gL1((NC + CHUNK - 1) / CHUNK, bs);
    int nBlocks = gL1.x * gL1.y;   // 200
    k_l1f<<<gL1, 128, 0, stream>>>(hpoolT, fcb, l1W, hpre, done, l1b, l2W, l2b, out,
                                   NC, HFC, bs, NCLS, CHUNK, nBlocks);
}